// Round 3
// baseline (266.083 us; speedup 1.0000x reference)
//
#include <hip/hip_runtime.h>

typedef __bf16 bf16;
typedef bf16 bf16x2 __attribute__((ext_vector_type(2)));
typedef bf16 bf16x4 __attribute__((ext_vector_type(4)));
typedef bf16 bf16x8 __attribute__((ext_vector_type(8)));
typedef float f32x4 __attribute__((ext_vector_type(4)));
typedef float f32x16 __attribute__((ext_vector_type(16)));
typedef int i32x2 __attribute__((ext_vector_type(2)));
typedef int i32x4 __attribute__((ext_vector_type(4)));

#define SEQ 256
#define DH  32
#define VT_PAD 264   // bf16 row stride 528B = 33*16B -> b128 col reads spread 8/bank (free)

// pack two f32 -> one dword of 2 bf16 (v_cvt_pk_bf16_f32)
static __device__ __forceinline__ int pk2(float a, float b) {
    bf16x2 t; t[0] = (bf16)a; t[1] = (bf16)b;
    return __builtin_bit_cast(int, t);
}

static __device__ __forceinline__ bf16x8 cvt8(f32x4 a, f32x4 b) {
    bf16x8 f;
    f[0]=(bf16)a[0]; f[1]=(bf16)a[1]; f[2]=(bf16)a[2]; f[3]=(bf16)a[3];
    f[4]=(bf16)b[0]; f[5]=(bf16)b[1]; f[6]=(bf16)b[2]; f[7]=(bf16)b[3];
    return f;
}

// One C-register group G of the 32x32 QK^T output -> exp2 -> two packed dwords
// covering t = 8G+4hi+{0..3}. All indices compile-time.
template<int G>
static __device__ __forceinline__ i32x2 pgrp(f32x16 cf, f32x4 tg, f32x4 mk, float& lp) {
    constexpr float K1    = 0.17677669529663687f * 1.44269504088896f; // sm_scale*log2e
    constexpr float LOG2E = 1.44269504088896f;
    float p0 = __builtin_amdgcn_exp2f(fmaf(cf[4*G+0], K1, fmaf(tg[0], LOG2E, mk[0])));
    float p1 = __builtin_amdgcn_exp2f(fmaf(cf[4*G+1], K1, fmaf(tg[1], LOG2E, mk[1])));
    float p2 = __builtin_amdgcn_exp2f(fmaf(cf[4*G+2], K1, fmaf(tg[2], LOG2E, mk[2])));
    float p3 = __builtin_amdgcn_exp2f(fmaf(cf[4*G+3], K1, fmaf(tg[3], LOG2E, mk[3])));
    lp += (p0 + p1) + (p2 + p3);
    i32x2 r; r[0] = pk2(p0, p1); r[1] = pk2(p2, p3);
    return r;
}

// 4 permlane32_swap -> two PV A-frags (t-local 0..15 and 16..31), pure vector ops
static __device__ __forceinline__ void frags(i32x2 a0, i32x2 a1, i32x2 a2, i32x2 a3,
                                             bf16x8& f0, bf16x8& f1) {
    i32x2 s0 = __builtin_amdgcn_permlane32_swap(a0[0], a1[0], false, false);
    i32x2 s1 = __builtin_amdgcn_permlane32_swap(a0[1], a1[1], false, false);
    i32x2 s2 = __builtin_amdgcn_permlane32_swap(a2[0], a3[0], false, false);
    i32x2 s3 = __builtin_amdgcn_permlane32_swap(a2[1], a3[1], false, false);
    i32x4 w0 = {s0[0], s1[0], s0[1], s1[1]};
    i32x4 w1 = {s2[0], s3[0], s2[1], s3[1]};
    f0 = __builtin_bit_cast(bf16x8, w0);
    f1 = __builtin_bit_cast(bf16x8, w1);
}

// S^T = K*Q^T with 32x32x16 MFMAs (M=t keys, N=s queries).
// C layout: col = s = lane&31, row = t = (reg&3) + 8*(reg>>2) + 4*(lane>>5).
// Grid: 2 blocks per (n,h) instance; each block = 4 waves x 32 queries.
__global__ __launch_bounds__(256, 4) void attn_mfma_kernel(
    const float* __restrict__ q,
    const float* __restrict__ k,
    const float* __restrict__ v,
    const float* __restrict__ mask_bias,   // [N][SEQ]
    const float* __restrict__ tri_bias,    // [H][SEQ][SEQ]
    float* __restrict__ out)
{
    __shared__ bf16 Vt[DH][VT_PAD];    // V^T: Vt[d][t], 16896 B
    __shared__ float Ml[SEQ];          // mask*log2e,     1024 B

    const int tid  = threadIdx.x;
    const int wave = tid >> 6;
    const int lane = tid & 63;
    const int l31  = lane & 31;
    const int hi   = lane >> 5;

    // XCD-aware swizzle (2048 = 8*256, bijective): same-instance block pairs
    // land on the same XCD -> shared q/k/v L2 lines.
    const int bid  = blockIdx.x;
    const int swz  = (bid & 7) * 256 + (bid >> 3);
    const int inst = swz >> 1;             // n*4 + h
    const int halfb= swz & 1;              // which 128-query half
    const int n    = inst >> 2;
    const int h    = inst & 3;

    const float* qb = q + (size_t)inst * SEQ * DH;
    const float* kb = k + (size_t)inst * SEQ * DH;
    const float* vb = v + (size_t)inst * SEQ * DH;
    const float* mb = mask_bias + (size_t)n * SEQ;
    const float* tb = tri_bias + (size_t)h * SEQ * SEQ;

    constexpr float LOG2E = 1.44269504088896f;

    const int qbase = halfb * 128 + wave * 32;   // this wave's 32 queries

    // per-lane tri row pointer: row s = qbase + l31, cols +4*hi
    const float* trow = tb + (size_t)(qbase + l31) * SEQ + 4 * hi;

    // ---- prefetch chunk 0: K frag sources + tri (in flight across staging) ----
    const float* kp0 = kb + (size_t)l31 * DH + hi * 8;
    f32x4 kA = ((const f32x4*)kp0)[0];
    f32x4 kB = ((const f32x4*)kp0)[1];
    f32x4 kC = ((const f32x4*)(kp0 + 16))[0];
    f32x4 kD = ((const f32x4*)(kp0 + 16))[1];
    f32x4 tp0 = *(const f32x4*)(trow + 0);
    f32x4 tp1 = *(const f32x4*)(trow + 8);
    f32x4 tp2 = *(const f32x4*)(trow + 16);
    f32x4 tp3 = *(const f32x4*)(trow + 24);

    // ---- Q b-frags: qfD = Q[qbase+l31][D*16 + hi*8 .. +7] ----
    bf16x8 qf0, qf1;
    {
        const float* p = qb + (size_t)(qbase + l31) * DH + hi * 8;
        qf0 = cvt8(((const f32x4*)p)[0], ((const f32x4*)p)[1]);
        qf1 = cvt8(((const f32x4*)(p + 16))[0], ((const f32x4*)(p + 16))[1]);
    }

    // ---- stage V^T (bf16) + mask*log2e into LDS ----
    #pragma unroll
    for (int i = 0; i < 8; ++i) {
        int idx = i * 256 + tid;       // float4 index: t = idx>>3, d-group = idx&7
        int t   = idx >> 3;
        int d4  = (idx & 7) * 4;
        f32x4 tv = ((const f32x4*)vb)[idx];
        Vt[d4 + 0][t] = (bf16)tv[0];
        Vt[d4 + 1][t] = (bf16)tv[1];
        Vt[d4 + 2][t] = (bf16)tv[2];
        Vt[d4 + 3][t] = (bf16)tv[3];
    }
    Ml[tid] = mb[tid] * LOG2E;
    __syncthreads();

    f32x16 oacc = {};
    float lp = 0.f;
    const f32x16 z16 = {};

    // ---- main loop: 8 chunks of 32 keys, K+tri prefetched one chunk ahead ----
    for (int c = 0; c < 8; ++c) {
        const int tb0 = c * 32;

        // consume prefetched K (loaded a full chunk ago)
        bf16x8 kf0 = cvt8(kA, kB);
        bf16x8 kf1 = cvt8(kC, kD);
        f32x4 t0 = tp0, t1 = tp1, t2 = tp2, t3 = tp3;

        // issue next chunk's K + tri loads (full chunk of latency cover)
        if (c < 7) {
            const float* kp = kb + (size_t)(tb0 + 32 + l31) * DH + hi * 8;
            kA = ((const f32x4*)kp)[0];
            kB = ((const f32x4*)kp)[1];
            kC = ((const f32x4*)(kp + 16))[0];
            kD = ((const f32x4*)(kp + 16))[1];
            tp0 = *(const f32x4*)(trow + tb0 + 32);
            tp1 = *(const f32x4*)(trow + tb0 + 40);
            tp2 = *(const f32x4*)(trow + tb0 + 48);
            tp3 = *(const f32x4*)(trow + tb0 + 56);
        }

        // mask*log2e (LDS broadcast): t = tb0 + 8g + 4hi + {0..3}
        f32x4 mk0 = *(const f32x4*)&Ml[tb0 +  0 + 4 * hi];
        f32x4 mk1 = *(const f32x4*)&Ml[tb0 +  8 + 4 * hi];
        f32x4 mk2 = *(const f32x4*)&Ml[tb0 + 16 + 4 * hi];
        f32x4 mk3 = *(const f32x4*)&Ml[tb0 + 24 + 4 * hi];

        // QK^T
        f32x16 cf = __builtin_amdgcn_mfma_f32_32x32x16_bf16(kf0, qf0, z16, 0, 0, 0);
        cf = __builtin_amdgcn_mfma_f32_32x32x16_bf16(kf1, qf1, cf, 0, 0, 0);

        // softmax numerator + pack
        i32x2 a0 = pgrp<0>(cf, t0, mk0, lp);
        i32x2 a1 = pgrp<1>(cf, t1, mk1, lp);
        i32x2 a2 = pgrp<2>(cf, t2, mk2, lp);
        i32x2 a3 = pgrp<3>(cf, t3, mk3, lp);
        bf16x8 pa0, pa1;
        frags(a0, a1, a2, a3, pa0, pa1);

        // V b-frags from LDS: Vt[l31][tb0 + tau*16 + hi*8 .. +7]
        bf16x8 vf0 = *(const bf16x8*)&Vt[l31][tb0 + hi * 8];
        bf16x8 vf1 = *(const bf16x8*)&Vt[l31][tb0 + 16 + hi * 8];

        oacc = __builtin_amdgcn_mfma_f32_32x32x16_bf16(pa0, vf0, oacc, 0, 0, 0);
        oacc = __builtin_amdgcn_mfma_f32_32x32x16_bf16(pa1, vf1, oacc, 0, 0, 0);
    }

    // ---- softmax denominator: hi-half reduce, then normalize + store ----
    lp += __shfl_xor(lp, 32);
    const float linv = 1.0f / lp;      // valid for s = qbase + l31

    float* ob = out + (size_t)inst * SEQ * DH;
    #pragma unroll
    for (int r = 0; r < 16; ++r) {
        const int srow = (r & 3) + 8 * (r >> 2) + 4 * hi;
        float invr = __shfl(linv, srow);   // 1/l for row srow lives in lane srow
        ob[(size_t)(qbase + srow) * DH + l31] = oacc[r] * invr;
    }
}

extern "C" void kernel_launch(void* const* d_in, const int* in_sizes, int n_in,
                              void* d_out, int out_size, void* d_ws, size_t ws_size,
                              hipStream_t stream) {
    const float* q    = (const float*)d_in[0];
    const float* k    = (const float*)d_in[1];
    const float* v    = (const float*)d_in[2];
    const float* mask = (const float*)d_in[3];
    const float* tri  = (const float*)d_in[4];
    float* out = (float*)d_out;

    attn_mfma_kernel<<<dim3(2048), dim3(256), 0, stream>>>(q, k, v, mask, tri, out);
}

// Round 4
// 193.425 us; speedup vs baseline: 1.3756x; 1.3756x over previous
//
#include <hip/hip_runtime.h>

typedef __bf16 bf16;
typedef bf16 bf16x2 __attribute__((ext_vector_type(2)));
typedef bf16 bf16x4 __attribute__((ext_vector_type(4)));
typedef bf16 bf16x8 __attribute__((ext_vector_type(8)));
typedef float f32x4 __attribute__((ext_vector_type(4)));
typedef float f32x16 __attribute__((ext_vector_type(16)));
typedef int i32x2 __attribute__((ext_vector_type(2)));
typedef int i32x4 __attribute__((ext_vector_type(4)));

#define SEQ 256
#define DH  32
#define VT_PAD 264   // bf16 row stride 528B = 33*16B -> b128 col reads spread 8/bank (free)

// pack two f32 -> one dword of 2 bf16 (v_cvt_pk_bf16_f32)
static __device__ __forceinline__ int pk2(float a, float b) {
    bf16x2 t; t[0] = (bf16)a; t[1] = (bf16)b;
    return __builtin_bit_cast(int, t);
}

static __device__ __forceinline__ bf16x8 cvt8(f32x4 a, f32x4 b) {
    bf16x8 f;
    f[0]=(bf16)a[0]; f[1]=(bf16)a[1]; f[2]=(bf16)a[2]; f[3]=(bf16)a[3];
    f[4]=(bf16)b[0]; f[5]=(bf16)b[1]; f[6]=(bf16)b[2]; f[7]=(bf16)b[3];
    return f;
}

// One C-register group G of the 32x32 QK^T output -> exp2 -> two packed dwords
// covering t = 8G+4hi+{0..3}. All indices compile-time.
template<int G>
static __device__ __forceinline__ i32x2 pgrp(f32x16 cf, f32x4 tg, f32x4 mk, float& lp) {
    constexpr float K1    = 0.17677669529663687f * 1.44269504088896f; // sm_scale*log2e
    constexpr float LOG2E = 1.44269504088896f;
    float p0 = __builtin_amdgcn_exp2f(fmaf(cf[4*G+0], K1, fmaf(tg[0], LOG2E, mk[0])));
    float p1 = __builtin_amdgcn_exp2f(fmaf(cf[4*G+1], K1, fmaf(tg[1], LOG2E, mk[1])));
    float p2 = __builtin_amdgcn_exp2f(fmaf(cf[4*G+2], K1, fmaf(tg[2], LOG2E, mk[2])));
    float p3 = __builtin_amdgcn_exp2f(fmaf(cf[4*G+3], K1, fmaf(tg[3], LOG2E, mk[3])));
    lp += (p0 + p1) + (p2 + p3);
    i32x2 r; r[0] = pk2(p0, p1); r[1] = pk2(p2, p3);
    return r;
}

// 4 permlane32_swap -> two PV A-frags (t-local 0..15 and 16..31), pure vector ops
static __device__ __forceinline__ void frags(i32x2 a0, i32x2 a1, i32x2 a2, i32x2 a3,
                                             bf16x8& f0, bf16x8& f1) {
    i32x2 s0 = __builtin_amdgcn_permlane32_swap(a0[0], a1[0], false, false);
    i32x2 s1 = __builtin_amdgcn_permlane32_swap(a0[1], a1[1], false, false);
    i32x2 s2 = __builtin_amdgcn_permlane32_swap(a2[0], a3[0], false, false);
    i32x2 s3 = __builtin_amdgcn_permlane32_swap(a2[1], a3[1], false, false);
    i32x4 w0 = {s0[0], s1[0], s0[1], s1[1]};
    i32x4 w1 = {s2[0], s3[0], s2[1], s3[1]};
    f0 = __builtin_bit_cast(bf16x8, w0);
    f1 = __builtin_bit_cast(bf16x8, w1);
}

// S^T = K*Q^T with 32x32x16 MFMAs (M=t keys, N=s queries).
// C layout: col = s = lane&31, row = t = (reg&3) + 8*(reg>>2) + 4*(lane>>5).
// Grid: 2 blocks per (n,h) instance; each block = 4 waves x 32 queries.
// NOTE: __launch_bounds__(256,2) NOT (256,4): min-waves/EU=4 forces the
// allocator to ~64 VGPR and spills prefetch+acc state to scratch
// (R1: 456MB, R3: 235MB phantom WRITE_SIZE). (256,2) measured spill-free.
__global__ __launch_bounds__(256, 2) void attn_mfma_kernel(
    const float* __restrict__ q,
    const float* __restrict__ k,
    const float* __restrict__ v,
    const float* __restrict__ mask_bias,   // [N][SEQ]
    const float* __restrict__ tri_bias,    // [H][SEQ][SEQ]
    float* __restrict__ out)
{
    __shared__ bf16 Vt[DH][VT_PAD];    // V^T: Vt[d][t], 16896 B
    __shared__ float Ml[SEQ];          // mask*log2e,     1024 B

    const int tid  = threadIdx.x;
    const int wave = tid >> 6;
    const int lane = tid & 63;
    const int l31  = lane & 31;
    const int hi   = lane >> 5;

    // XCD-aware swizzle (2048 = 8*256, bijective): same-instance block pairs
    // land on the same XCD -> shared q/k/v L2 lines.
    const int bid  = blockIdx.x;
    const int swz  = (bid & 7) * 256 + (bid >> 3);
    const int inst = swz >> 1;             // n*4 + h
    const int halfb= swz & 1;              // which 128-query half
    const int n    = inst >> 2;
    const int h    = inst & 3;

    const float* qb = q + (size_t)inst * SEQ * DH;
    const float* kb = k + (size_t)inst * SEQ * DH;
    const float* vb = v + (size_t)inst * SEQ * DH;
    const float* mb = mask_bias + (size_t)n * SEQ;
    const float* tb = tri_bias + (size_t)h * SEQ * SEQ;

    constexpr float LOG2E = 1.44269504088896f;

    const int qbase = halfb * 128 + wave * 32;   // this wave's 32 queries

    // per-lane tri row pointer: row s = qbase + l31, cols +4*hi
    const float* trow = tb + (size_t)(qbase + l31) * SEQ + 4 * hi;

    // ---- prefetch chunk 0: K frag sources + tri (in flight across staging) ----
    const float* kp0 = kb + (size_t)l31 * DH + hi * 8;
    f32x4 kA = ((const f32x4*)kp0)[0];
    f32x4 kB = ((const f32x4*)kp0)[1];
    f32x4 kC = ((const f32x4*)(kp0 + 16))[0];
    f32x4 kD = ((const f32x4*)(kp0 + 16))[1];
    f32x4 tp0 = *(const f32x4*)(trow + 0);
    f32x4 tp1 = *(const f32x4*)(trow + 8);
    f32x4 tp2 = *(const f32x4*)(trow + 16);
    f32x4 tp3 = *(const f32x4*)(trow + 24);

    // ---- Q b-frags: qfD = Q[qbase+l31][D*16 + hi*8 .. +7] ----
    bf16x8 qf0, qf1;
    {
        const float* p = qb + (size_t)(qbase + l31) * DH + hi * 8;
        qf0 = cvt8(((const f32x4*)p)[0], ((const f32x4*)p)[1]);
        qf1 = cvt8(((const f32x4*)(p + 16))[0], ((const f32x4*)(p + 16))[1]);
    }

    // ---- stage V^T (bf16) + mask*log2e into LDS ----
    #pragma unroll
    for (int i = 0; i < 8; ++i) {
        int idx = i * 256 + tid;       // float4 index: t = idx>>3, d-group = idx&7
        int t   = idx >> 3;
        int d4  = (idx & 7) * 4;
        f32x4 tv = ((const f32x4*)vb)[idx];
        Vt[d4 + 0][t] = (bf16)tv[0];
        Vt[d4 + 1][t] = (bf16)tv[1];
        Vt[d4 + 2][t] = (bf16)tv[2];
        Vt[d4 + 3][t] = (bf16)tv[3];
    }
    Ml[tid] = mb[tid] * LOG2E;
    __syncthreads();

    f32x16 oacc = {};
    float lp = 0.f;
    const f32x16 z16 = {};

    // ---- main loop: 8 chunks of 32 keys, K+tri prefetched one chunk ahead ----
    for (int c = 0; c < 8; ++c) {
        const int tb0 = c * 32;

        // consume prefetched K (loaded a full chunk ago)
        bf16x8 kf0 = cvt8(kA, kB);
        bf16x8 kf1 = cvt8(kC, kD);
        f32x4 t0 = tp0, t1 = tp1, t2 = tp2, t3 = tp3;

        // issue next chunk's K + tri loads (full chunk of latency cover)
        if (c < 7) {
            const float* kp = kb + (size_t)(tb0 + 32 + l31) * DH + hi * 8;
            kA = ((const f32x4*)kp)[0];
            kB = ((const f32x4*)kp)[1];
            kC = ((const f32x4*)(kp + 16))[0];
            kD = ((const f32x4*)(kp + 16))[1];
            tp0 = *(const f32x4*)(trow + tb0 + 32);
            tp1 = *(const f32x4*)(trow + tb0 + 40);
            tp2 = *(const f32x4*)(trow + tb0 + 48);
            tp3 = *(const f32x4*)(trow + tb0 + 56);
        }

        // mask*log2e (LDS broadcast): t = tb0 + 8g + 4hi + {0..3}
        f32x4 mk0 = *(const f32x4*)&Ml[tb0 +  0 + 4 * hi];
        f32x4 mk1 = *(const f32x4*)&Ml[tb0 +  8 + 4 * hi];
        f32x4 mk2 = *(const f32x4*)&Ml[tb0 + 16 + 4 * hi];
        f32x4 mk3 = *(const f32x4*)&Ml[tb0 + 24 + 4 * hi];

        // QK^T
        f32x16 cf = __builtin_amdgcn_mfma_f32_32x32x16_bf16(kf0, qf0, z16, 0, 0, 0);
        cf = __builtin_amdgcn_mfma_f32_32x32x16_bf16(kf1, qf1, cf, 0, 0, 0);

        // softmax numerator + pack
        i32x2 a0 = pgrp<0>(cf, t0, mk0, lp);
        i32x2 a1 = pgrp<1>(cf, t1, mk1, lp);
        i32x2 a2 = pgrp<2>(cf, t2, mk2, lp);
        i32x2 a3 = pgrp<3>(cf, t3, mk3, lp);
        bf16x8 pa0, pa1;
        frags(a0, a1, a2, a3, pa0, pa1);

        // V b-frags from LDS: Vt[l31][tb0 + tau*16 + hi*8 .. +7]
        bf16x8 vf0 = *(const bf16x8*)&Vt[l31][tb0 + hi * 8];
        bf16x8 vf1 = *(const bf16x8*)&Vt[l31][tb0 + 16 + hi * 8];

        oacc = __builtin_amdgcn_mfma_f32_32x32x16_bf16(pa0, vf0, oacc, 0, 0, 0);
        oacc = __builtin_amdgcn_mfma_f32_32x32x16_bf16(pa1, vf1, oacc, 0, 0, 0);
    }

    // ---- softmax denominator: hi-half reduce, then normalize + store ----
    lp += __shfl_xor(lp, 32);
    const float linv = 1.0f / lp;      // valid for s = qbase + l31

    float* ob = out + (size_t)inst * SEQ * DH;
    #pragma unroll
    for (int r = 0; r < 16; ++r) {
        const int srow = (r & 3) + 8 * (r >> 2) + 4 * hi;
        float invr = __shfl(linv, srow);   // 1/l for row srow lives in lane srow
        ob[(size_t)(qbase + srow) * DH + l31] = oacc[r] * invr;
    }
}

extern "C" void kernel_launch(void* const* d_in, const int* in_sizes, int n_in,
                              void* d_out, int out_size, void* d_ws, size_t ws_size,
                              hipStream_t stream) {
    const float* q    = (const float*)d_in[0];
    const float* k    = (const float*)d_in[1];
    const float* v    = (const float*)d_in[2];
    const float* mask = (const float*)d_in[3];
    const float* tri  = (const float*)d_in[4];
    float* out = (float*)d_out;

    attn_mfma_kernel<<<dim3(2048), dim3(256), 0, stream>>>(q, k, v, mask, tri, out);
}

// Round 5
// 168.105 us; speedup vs baseline: 1.5828x; 1.1506x over previous
//
#include <hip/hip_runtime.h>

typedef __bf16 bf16;
typedef bf16 bf16x2 __attribute__((ext_vector_type(2)));
typedef bf16 bf16x4 __attribute__((ext_vector_type(4)));
typedef bf16 bf16x8 __attribute__((ext_vector_type(8)));
typedef float f32x4 __attribute__((ext_vector_type(4)));
typedef float f32x16 __attribute__((ext_vector_type(16)));
typedef int i32x2 __attribute__((ext_vector_type(2)));
typedef int i32x4 __attribute__((ext_vector_type(4)));

#define SEQ 256
#define DH  32
#define VT_PAD 264   // bf16 row stride 528B = 33*16B -> b128 col reads spread 8/bank (free)

// pack two f32 -> one dword of 2 bf16 (v_cvt_pk_bf16_f32)
static __device__ __forceinline__ int pk2(float a, float b) {
    bf16x2 t; t[0] = (bf16)a; t[1] = (bf16)b;
    return __builtin_bit_cast(int, t);
}

static __device__ __forceinline__ bf16x8 cvt8(f32x4 a, f32x4 b) {
    bf16x8 f;
    f[0]=(bf16)a[0]; f[1]=(bf16)a[1]; f[2]=(bf16)a[2]; f[3]=(bf16)a[3];
    f[4]=(bf16)b[0]; f[5]=(bf16)b[1]; f[6]=(bf16)b[2]; f[7]=(bf16)b[3];
    return f;
}

// One C-register group G of the 32x32 QK^T output -> exp2 -> two packed dwords
// covering t = 8G+4hi+{0..3}. All indices compile-time.
template<int G>
static __device__ __forceinline__ i32x2 pgrp(f32x16 cf, f32x4 tg, f32x4 mk, float& lp) {
    constexpr float K1    = 0.17677669529663687f * 1.44269504088896f; // sm_scale*log2e
    constexpr float LOG2E = 1.44269504088896f;
    float p0 = __builtin_amdgcn_exp2f(fmaf(cf[4*G+0], K1, fmaf(tg[0], LOG2E, mk[0])));
    float p1 = __builtin_amdgcn_exp2f(fmaf(cf[4*G+1], K1, fmaf(tg[1], LOG2E, mk[1])));
    float p2 = __builtin_amdgcn_exp2f(fmaf(cf[4*G+2], K1, fmaf(tg[2], LOG2E, mk[2])));
    float p3 = __builtin_amdgcn_exp2f(fmaf(cf[4*G+3], K1, fmaf(tg[3], LOG2E, mk[3])));
    lp += (p0 + p1) + (p2 + p3);
    i32x2 r; r[0] = pk2(p0, p1); r[1] = pk2(p2, p3);
    return r;
}

// 4 permlane32_swap -> two PV A-frags (t-local 0..15 and 16..31), pure vector ops
static __device__ __forceinline__ void frags(i32x2 a0, i32x2 a1, i32x2 a2, i32x2 a3,
                                             bf16x8& f0, bf16x8& f1) {
    i32x2 s0 = __builtin_amdgcn_permlane32_swap(a0[0], a1[0], false, false);
    i32x2 s1 = __builtin_amdgcn_permlane32_swap(a0[1], a1[1], false, false);
    i32x2 s2 = __builtin_amdgcn_permlane32_swap(a2[0], a3[0], false, false);
    i32x2 s3 = __builtin_amdgcn_permlane32_swap(a2[1], a3[1], false, false);
    i32x4 w0 = {s0[0], s1[0], s0[1], s1[1]};
    i32x4 w1 = {s2[0], s3[0], s2[1], s3[1]};
    f0 = __builtin_bit_cast(bf16x8, w0);
    f1 = __builtin_bit_cast(bf16x8, w1);
}

// S^T = K*Q^T with 32x32x16 MFMAs (M=t keys, N=s queries).
// C layout: col = s = lane&31, row = t = (reg&3) + 8*(reg>>2) + 4*(lane>>5).
// Topology (best measured, R2): 1 block per (n,h); 4 waves x 64 queries (2 stiles).
// K: register-prefetched one chunk ahead (R4-validated), shared by both stiles.
// NOTE: __launch_bounds__(256,2), NOT (256,4): min-waves/EU=4 squeezes to 64 VGPR
// and spills prefetch+acc to scratch (R1: 456MB, R3: 235MB phantom WRITE_SIZE).
__global__ __launch_bounds__(256, 2) void attn_mfma_kernel(
    const float* __restrict__ q,
    const float* __restrict__ k,
    const float* __restrict__ v,
    const float* __restrict__ mask_bias,   // [N][SEQ]
    const float* __restrict__ tri_bias,    // [H][SEQ][SEQ]
    float* __restrict__ out)
{
    __shared__ bf16 Vt[DH][VT_PAD];    // V^T: Vt[d][t], 16896 B
    __shared__ float Ml[SEQ];          // mask*log2e,     1024 B  (17.9 KB total)

    const int tid  = threadIdx.x;
    const int wave = tid >> 6;
    const int lane = tid & 63;
    const int l31  = lane & 31;
    const int hi   = lane >> 5;

    const int inst = blockIdx.x;       // n*4 + h
    const int n    = inst >> 2;
    const int h    = inst & 3;

    const float* qb = q + (size_t)inst * SEQ * DH;
    const float* kb = k + (size_t)inst * SEQ * DH;
    const float* vb = v + (size_t)inst * SEQ * DH;
    const float* mb = mask_bias + (size_t)n * SEQ;
    const float* tb = tri_bias + (size_t)h * SEQ * SEQ;

    constexpr float LOG2E = 1.44269504088896f;

    const int sbase = wave * 64;       // wave owns 64 queries = 2 stiles of 32

    // per-lane tri row pointers: row s = sbase + st*32 + l31, cols +4*hi
    const float* trow0 = tb + (size_t)(sbase + l31) * SEQ + 4 * hi;
    const float* trow1 = trow0 + 32 * SEQ;

    // ---- prefetch chunk 0: K frag sources + tri stile0 (in flight across staging) ----
    const float* kp0 = kb + (size_t)l31 * DH + hi * 8;
    f32x4 kA = ((const f32x4*)kp0)[0];
    f32x4 kB = ((const f32x4*)kp0)[1];
    f32x4 kC = ((const f32x4*)(kp0 + 16))[0];
    f32x4 kD = ((const f32x4*)(kp0 + 16))[1];
    f32x4 tp0 = *(const f32x4*)(trow0 + 0);
    f32x4 tp1 = *(const f32x4*)(trow0 + 8);
    f32x4 tp2 = *(const f32x4*)(trow0 + 16);
    f32x4 tp3 = *(const f32x4*)(trow0 + 24);

    // ---- Q b-frags: qfSD = Q[sbase+S*32+l31][D*16 + hi*8 .. +7] ----
    bf16x8 qf00, qf01, qf10, qf11;
    {
        const float* p0 = qb + (size_t)(sbase + l31) * DH + hi * 8;
        const float* p1 = qb + (size_t)(sbase + 32 + l31) * DH + hi * 8;
        qf00 = cvt8(((const f32x4*)p0)[0], ((const f32x4*)p0)[1]);
        qf01 = cvt8(((const f32x4*)(p0 + 16))[0], ((const f32x4*)(p0 + 16))[1]);
        qf10 = cvt8(((const f32x4*)p1)[0], ((const f32x4*)p1)[1]);
        qf11 = cvt8(((const f32x4*)(p1 + 16))[0], ((const f32x4*)(p1 + 16))[1]);
    }

    // ---- stage V^T (bf16) + mask*log2e into LDS ----
    #pragma unroll
    for (int i = 0; i < 8; ++i) {
        int idx = i * 256 + tid;       // float4 index: t = idx>>3, d-group = idx&7
        int t   = idx >> 3;
        int d4  = (idx & 7) * 4;
        f32x4 tv = ((const f32x4*)vb)[idx];
        Vt[d4 + 0][t] = (bf16)tv[0];
        Vt[d4 + 1][t] = (bf16)tv[1];
        Vt[d4 + 2][t] = (bf16)tv[2];
        Vt[d4 + 3][t] = (bf16)tv[3];
    }
    Ml[tid] = mb[tid] * LOG2E;
    __syncthreads();

    f32x16 oacc0 = {}, oacc1 = {};
    float lp0 = 0.f, lp1 = 0.f;
    const f32x16 z16 = {};

    // ---- main loop: 8 chunks of 32 keys; K + tri-stile0 prefetched a chunk ahead ----
    for (int c = 0; c < 8; ++c) {
        const int tb0 = c * 32;

        // consume prefetched K (loaded a full chunk ago); shared by both stiles
        bf16x8 kf0 = cvt8(kA, kB);
        bf16x8 kf1 = cvt8(kC, kD);
        f32x4 t0 = tp0, t1 = tp1, t2 = tp2, t3 = tp3;

        // issue tri stile1 loads now (consumed after stile0 -> latency covered)
        f32x4 u0 = *(const f32x4*)(trow1 + tb0 + 0);
        f32x4 u1 = *(const f32x4*)(trow1 + tb0 + 8);
        f32x4 u2 = *(const f32x4*)(trow1 + tb0 + 16);
        f32x4 u3 = *(const f32x4*)(trow1 + tb0 + 24);

        // issue next chunk's K + tri-stile0 loads (full chunk of latency cover)
        if (c < 7) {
            const float* kp = kb + (size_t)(tb0 + 32 + l31) * DH + hi * 8;
            kA = ((const f32x4*)kp)[0];
            kB = ((const f32x4*)kp)[1];
            kC = ((const f32x4*)(kp + 16))[0];
            kD = ((const f32x4*)(kp + 16))[1];
            tp0 = *(const f32x4*)(trow0 + tb0 + 32);
            tp1 = *(const f32x4*)(trow0 + tb0 + 40);
            tp2 = *(const f32x4*)(trow0 + tb0 + 48);
            tp3 = *(const f32x4*)(trow0 + tb0 + 56);
        }

        // V b-frags: issue LDS reads at chunk top so ~120cy ds latency hides
        // under QK + softmax (consumed only at the PV step below)
        bf16x8 vf0 = *(const bf16x8*)&Vt[l31][tb0 + hi * 8];
        bf16x8 vf1 = *(const bf16x8*)&Vt[l31][tb0 + 16 + hi * 8];

        // mask*log2e (LDS broadcast): t = tb0 + 8g + 4hi + {0..3}
        f32x4 mk0 = *(const f32x4*)&Ml[tb0 +  0 + 4 * hi];
        f32x4 mk1 = *(const f32x4*)&Ml[tb0 +  8 + 4 * hi];
        f32x4 mk2 = *(const f32x4*)&Ml[tb0 + 16 + 4 * hi];
        f32x4 mk3 = *(const f32x4*)&Ml[tb0 + 24 + 4 * hi];

        // ============ stile 0 ============
        __builtin_amdgcn_s_setprio(1);
        f32x16 cf = __builtin_amdgcn_mfma_f32_32x32x16_bf16(kf0, qf00, z16, 0, 0, 0);
        cf = __builtin_amdgcn_mfma_f32_32x32x16_bf16(kf1, qf01, cf, 0, 0, 0);
        __builtin_amdgcn_s_setprio(0);

        i32x2 a0 = pgrp<0>(cf, t0, mk0, lp0);
        i32x2 a1 = pgrp<1>(cf, t1, mk1, lp0);
        i32x2 a2 = pgrp<2>(cf, t2, mk2, lp0);
        i32x2 a3 = pgrp<3>(cf, t3, mk3, lp0);
        bf16x8 pa0, pa1;
        frags(a0, a1, a2, a3, pa0, pa1);

        __builtin_amdgcn_s_setprio(1);
        oacc0 = __builtin_amdgcn_mfma_f32_32x32x16_bf16(pa0, vf0, oacc0, 0, 0, 0);
        oacc0 = __builtin_amdgcn_mfma_f32_32x32x16_bf16(pa1, vf1, oacc0, 0, 0, 0);

        // ============ stile 1 ============
        cf = __builtin_amdgcn_mfma_f32_32x32x16_bf16(kf0, qf10, z16, 0, 0, 0);
        cf = __builtin_amdgcn_mfma_f32_32x32x16_bf16(kf1, qf11, cf, 0, 0, 0);
        __builtin_amdgcn_s_setprio(0);

        a0 = pgrp<0>(cf, u0, mk0, lp1);
        a1 = pgrp<1>(cf, u1, mk1, lp1);
        a2 = pgrp<2>(cf, u2, mk2, lp1);
        a3 = pgrp<3>(cf, u3, mk3, lp1);
        bf16x8 pb0, pb1;
        frags(a0, a1, a2, a3, pb0, pb1);

        __builtin_amdgcn_s_setprio(1);
        oacc1 = __builtin_amdgcn_mfma_f32_32x32x16_bf16(pb0, vf0, oacc1, 0, 0, 0);
        oacc1 = __builtin_amdgcn_mfma_f32_32x32x16_bf16(pb1, vf1, oacc1, 0, 0, 0);
        __builtin_amdgcn_s_setprio(0);
    }

    // ---- softmax denominators: hi-half reduce, then normalize + store ----
    lp0 += __shfl_xor(lp0, 32);
    lp1 += __shfl_xor(lp1, 32);
    const float li0 = 1.0f / lp0;      // valid for s = sbase + l31
    const float li1 = 1.0f / lp1;      // valid for s = sbase + 32 + l31

    float* ob = out + (size_t)inst * SEQ * DH;
    #pragma unroll
    for (int r = 0; r < 16; ++r) {
        const int srow = (r & 3) + 8 * (r >> 2) + 4 * hi;
        float i0 = __shfl(li0, srow);  // 1/l for row srow lives in lane srow
        float i1 = __shfl(li1, srow);
        ob[(size_t)(sbase + srow) * DH + l31]      = oacc0[r] * i0;
        ob[(size_t)(sbase + 32 + srow) * DH + l31] = oacc1[r] * i1;
    }
}

extern "C" void kernel_launch(void* const* d_in, const int* in_sizes, int n_in,
                              void* d_out, int out_size, void* d_ws, size_t ws_size,
                              hipStream_t stream) {
    const float* q    = (const float*)d_in[0];
    const float* k    = (const float*)d_in[1];
    const float* v    = (const float*)d_in[2];
    const float* mask = (const float*)d_in[3];
    const float* tri  = (const float*)d_in[4];
    float* out = (float*)d_out;

    attn_mfma_kernel<<<dim3(256 * 4), dim3(256), 0, stream>>>(q, k, v, mask, tri, out);
}

// Round 6
// 151.369 us; speedup vs baseline: 1.7578x; 1.1106x over previous
//
#include <hip/hip_runtime.h>

typedef __bf16 bf16;
typedef bf16 bf16x2 __attribute__((ext_vector_type(2)));
typedef bf16 bf16x4 __attribute__((ext_vector_type(4)));
typedef bf16 bf16x8 __attribute__((ext_vector_type(8)));
typedef float f32x4 __attribute__((ext_vector_type(4)));
typedef float f32x16 __attribute__((ext_vector_type(16)));
typedef int i32x2 __attribute__((ext_vector_type(2)));
typedef int i32x4 __attribute__((ext_vector_type(4)));

#define SEQ 256
#define DH  32
#define VT_PAD 264   // bf16 row stride 528B = 33*16B
#define KB_PAD 40    // bf16 row stride  80B =  5*16B
#define TRP 36       // tri tile padded cols (floats): row 144B -> 4-bank shift/row

// pack two f32 -> one dword of 2 bf16 (v_cvt_pk_bf16_f32)
static __device__ __forceinline__ int pk2(float a, float b) {
    bf16x2 t; t[0] = (bf16)a; t[1] = (bf16)b;
    return __builtin_bit_cast(int, t);
}

static __device__ __forceinline__ bf16x8 cvt8(f32x4 a, f32x4 b) {
    bf16x8 f;
    f[0]=(bf16)a[0]; f[1]=(bf16)a[1]; f[2]=(bf16)a[2]; f[3]=(bf16)a[3];
    f[4]=(bf16)b[0]; f[5]=(bf16)b[1]; f[6]=(bf16)b[2]; f[7]=(bf16)b[3];
    return f;
}

// One C-register group G of the 32x32 QK^T output -> exp2 -> two packed dwords
// covering t = 8G+4hi+{0..3}. All indices compile-time.
template<int G>
static __device__ __forceinline__ i32x2 pgrp(f32x16 cf, f32x4 tg, f32x4 mk, float& lp) {
    constexpr float K1    = 0.17677669529663687f * 1.44269504088896f; // sm_scale*log2e
    constexpr float LOG2E = 1.44269504088896f;
    float p0 = __builtin_amdgcn_exp2f(fmaf(cf[4*G+0], K1, fmaf(tg[0], LOG2E, mk[0])));
    float p1 = __builtin_amdgcn_exp2f(fmaf(cf[4*G+1], K1, fmaf(tg[1], LOG2E, mk[1])));
    float p2 = __builtin_amdgcn_exp2f(fmaf(cf[4*G+2], K1, fmaf(tg[2], LOG2E, mk[2])));
    float p3 = __builtin_amdgcn_exp2f(fmaf(cf[4*G+3], K1, fmaf(tg[3], LOG2E, mk[3])));
    lp += (p0 + p1) + (p2 + p3);
    i32x2 r; r[0] = pk2(p0, p1); r[1] = pk2(p2, p3);
    return r;
}

// 4 permlane32_swap -> two PV A-frags (t-local 0..15 and 16..31)
static __device__ __forceinline__ void frags(i32x2 a0, i32x2 a1, i32x2 a2, i32x2 a3,
                                             bf16x8& f0, bf16x8& f1) {
    i32x2 s0 = __builtin_amdgcn_permlane32_swap(a0[0], a1[0], false, false);
    i32x2 s1 = __builtin_amdgcn_permlane32_swap(a0[1], a1[1], false, false);
    i32x2 s2 = __builtin_amdgcn_permlane32_swap(a2[0], a3[0], false, false);
    i32x2 s3 = __builtin_amdgcn_permlane32_swap(a2[1], a3[1], false, false);
    i32x4 w0 = {s0[0], s1[0], s0[1], s1[1]};
    i32x4 w1 = {s2[0], s3[0], s2[1], s3[1]};
    f0 = __builtin_bit_cast(bf16x8, w0);
    f1 = __builtin_bit_cast(bf16x8, w1);
}

// load one wave-private tri tile (64 rows x 32 cols, chunk cc) -> 8 named regs.
// Coalesced: instr i covers rows sbase+i*8..+7, each row a dense 128B segment.
#define LOAD_TRI(cc)                                              \
    sA = *(const f32x4*)(tstage + (cc) * 32 + 0 * 8 * SEQ);       \
    sB = *(const f32x4*)(tstage + (cc) * 32 + 1 * 8 * SEQ);       \
    sC = *(const f32x4*)(tstage + (cc) * 32 + 2 * 8 * SEQ);       \
    sD = *(const f32x4*)(tstage + (cc) * 32 + 3 * 8 * SEQ);       \
    sE = *(const f32x4*)(tstage + (cc) * 32 + 4 * 8 * SEQ);       \
    sF = *(const f32x4*)(tstage + (cc) * 32 + 5 * 8 * SEQ);       \
    sG = *(const f32x4*)(tstage + (cc) * 32 + 6 * 8 * SEQ);       \
    sH = *(const f32x4*)(tstage + (cc) * 32 + 7 * 8 * SEQ);

#define STORE_TRI()                                               \
    *(f32x4*)(twr + 0 * 8 * TRP) = sA;                            \
    *(f32x4*)(twr + 1 * 8 * TRP) = sB;                            \
    *(f32x4*)(twr + 2 * 8 * TRP) = sC;                            \
    *(f32x4*)(twr + 3 * 8 * TRP) = sD;                            \
    *(f32x4*)(twr + 4 * 8 * TRP) = sE;                            \
    *(f32x4*)(twr + 5 * 8 * TRP) = sF;                            \
    *(f32x4*)(twr + 6 * 8 * TRP) = sG;                            \
    *(f32x4*)(twr + 7 * 8 * TRP) = sH;

// S^T = K*Q^T with 32x32x16 MFMAs (M=t keys, N=s queries).
// C layout: col = s = lane&31, row = t = (reg&3) + 8*(reg>>2) + 4*(lane>>5).
// tri bias: staged coalesced global->reg->wave-private LDS tile (no barriers;
// same-wave DS ordering guarantees read-before-overwrite), 2 chunks ahead.
// NOTE: __launch_bounds__(256,2), NOT (256,4): waves/EU=4 squeezes to 64 VGPR
// and spills to scratch (R1: 456MB, R3: 235MB phantom WRITE_SIZE).
__global__ __launch_bounds__(256, 2) void attn_mfma_kernel(
    const float* __restrict__ q,
    const float* __restrict__ k,
    const float* __restrict__ v,
    const float* __restrict__ mask_bias,   // [N][SEQ]
    const float* __restrict__ tri_bias,    // [H][SEQ][SEQ]
    float* __restrict__ out)
{
    __shared__ __align__(16) bf16  Vt[DH][VT_PAD];   // V^T bf16: 16896 B
    __shared__ __align__(16) bf16  Kb[SEQ][KB_PAD];  // K bf16:   20480 B
    __shared__ __align__(16) float Ml[SEQ];          //            1024 B
    __shared__ __align__(16) float Tr[4][64][TRP];   // tri tiles: 36864 B (75.3 KB total)

    const int tid  = threadIdx.x;
    const int wave = tid >> 6;
    const int lane = tid & 63;
    const int l31  = lane & 31;
    const int hi   = lane >> 5;

    const int inst = blockIdx.x;       // n*4 + h
    const int n    = inst >> 2;
    const int h    = inst & 3;

    const float* qb = q + (size_t)inst * SEQ * DH;
    const float* kb = k + (size_t)inst * SEQ * DH;
    const float* vb = v + (size_t)inst * SEQ * DH;
    const float* mb = mask_bias + (size_t)n * SEQ;
    const float* tb = tri_bias + (size_t)h * SEQ * SEQ;

    constexpr float LOG2E = 1.44269504088896f;

    const int sbase = wave * 64;       // wave owns 64 queries = 2 stiles of 32

    // coalesced tri staging addresses (lane covers row sbase+(lane>>3)+i*8, 16B col lane&7)
    const float* tstage = tb + (size_t)(sbase + (lane >> 3)) * SEQ + (lane & 7) * 4;
    float*       twr    = &Tr[wave][lane >> 3][(lane & 7) * 4];

    f32x4 sA, sB, sC, sD, sE, sF, sG, sH;

    // ---- issue chunk0 tri loads first (in flight across all staging) ----
    LOAD_TRI(0);

    // ---- Q b-frags: qfSD = Q[sbase+S*32+l31][D*16 + hi*8 .. +7] ----
    bf16x8 qf00, qf01, qf10, qf11;
    {
        const float* p0 = qb + (size_t)(sbase + l31) * DH + hi * 8;
        const float* p1 = qb + (size_t)(sbase + 32 + l31) * DH + hi * 8;
        qf00 = cvt8(((const f32x4*)p0)[0], ((const f32x4*)p0)[1]);
        qf01 = cvt8(((const f32x4*)(p0 + 16))[0], ((const f32x4*)(p0 + 16))[1]);
        qf10 = cvt8(((const f32x4*)p1)[0], ((const f32x4*)p1)[1]);
        qf11 = cvt8(((const f32x4*)(p1 + 16))[0], ((const f32x4*)(p1 + 16))[1]);
    }

    // ---- stage V^T (bf16), K (bf16), mask*log2e into LDS (coalesced) ----
    #pragma unroll
    for (int i = 0; i < 8; ++i) {
        int idx = i * 256 + tid;       // float4 index: t = idx>>3, d-group = idx&7
        int t   = idx >> 3;
        int d4  = (idx & 7) * 4;
        f32x4 tv = ((const f32x4*)vb)[idx];
        Vt[d4 + 0][t] = (bf16)tv[0];
        Vt[d4 + 1][t] = (bf16)tv[1];
        Vt[d4 + 2][t] = (bf16)tv[2];
        Vt[d4 + 3][t] = (bf16)tv[3];
        f32x4 tk = ((const f32x4*)kb)[idx];
        bf16x4 kk;
        kk[0]=(bf16)tk[0]; kk[1]=(bf16)tk[1]; kk[2]=(bf16)tk[2]; kk[3]=(bf16)tk[3];
        *(bf16x4*)&Kb[t][d4] = kk;
    }
    Ml[tid] = mb[tid] * LOG2E;

    // write tri chunk0 tile, then start chunk1 loads (wave-local, no barrier)
    STORE_TRI();
    LOAD_TRI(1);

    __syncthreads();                   // for Vt/Kb/Ml only

    f32x16 oacc0 = {}, oacc1 = {};
    float lp0 = 0.f, lp1 = 0.f;
    const f32x16 z16 = {};

    // ---- main loop: 8 chunks of 32 keys ----
    for (int c = 0; c < 8; ++c) {
        const int tb0 = c * 32;

        // tri for chunk c from wave-private LDS tile (issued before tile overwrite)
        const float* trd = &Tr[wave][l31][hi * 4];          // col floats 8g+4hi
        f32x4 t0 = *(const f32x4*)(trd + 0);
        f32x4 t1 = *(const f32x4*)(trd + 8);
        f32x4 t2 = *(const f32x4*)(trd + 16);
        f32x4 t3 = *(const f32x4*)(trd + 24);
        f32x4 u0 = *(const f32x4*)(trd + 32 * TRP + 0);
        f32x4 u1 = *(const f32x4*)(trd + 32 * TRP + 8);
        f32x4 u2 = *(const f32x4*)(trd + 32 * TRP + 16);
        f32x4 u3 = *(const f32x4*)(trd + 32 * TRP + 24);

        // K a-frags + V b-frags from LDS
        bf16x8 kf0 = *(const bf16x8*)&Kb[tb0 + l31][hi * 8];
        bf16x8 kf1 = *(const bf16x8*)&Kb[tb0 + l31][16 + hi * 8];
        bf16x8 vf0 = *(const bf16x8*)&Vt[l31][tb0 + hi * 8];
        bf16x8 vf1 = *(const bf16x8*)&Vt[l31][tb0 + 16 + hi * 8];

        // mask*log2e (LDS broadcast): t = tb0 + 8g + 4hi + {0..3}
        f32x4 mk0 = *(const f32x4*)&Ml[tb0 +  0 + 4 * hi];
        f32x4 mk1 = *(const f32x4*)&Ml[tb0 +  8 + 4 * hi];
        f32x4 mk2 = *(const f32x4*)&Ml[tb0 + 16 + 4 * hi];
        f32x4 mk3 = *(const f32x4*)&Ml[tb0 + 24 + 4 * hi];

        // ============ stile 0 ============
        __builtin_amdgcn_s_setprio(1);
        f32x16 cf = __builtin_amdgcn_mfma_f32_32x32x16_bf16(kf0, qf00, z16, 0, 0, 0);
        cf = __builtin_amdgcn_mfma_f32_32x32x16_bf16(kf1, qf01, cf, 0, 0, 0);
        __builtin_amdgcn_s_setprio(0);

        i32x2 a0 = pgrp<0>(cf, t0, mk0, lp0);
        i32x2 a1 = pgrp<1>(cf, t1, mk1, lp0);
        i32x2 a2 = pgrp<2>(cf, t2, mk2, lp0);
        i32x2 a3 = pgrp<3>(cf, t3, mk3, lp0);
        bf16x8 pa0, pa1;
        frags(a0, a1, a2, a3, pa0, pa1);

        __builtin_amdgcn_s_setprio(1);
        oacc0 = __builtin_amdgcn_mfma_f32_32x32x16_bf16(pa0, vf0, oacc0, 0, 0, 0);
        oacc0 = __builtin_amdgcn_mfma_f32_32x32x16_bf16(pa1, vf1, oacc0, 0, 0, 0);
        __builtin_amdgcn_s_setprio(0);

        // tile maintenance: write chunk c+1 (regs loaded last iter), start c+2.
        // Safe vs the t/u reads above: same-wave DS ops execute in order.
        if (c < 7) { STORE_TRI(); }
        if (c < 6) { LOAD_TRI(c + 2); }

        // ============ stile 1 ============
        __builtin_amdgcn_s_setprio(1);
        cf = __builtin_amdgcn_mfma_f32_32x32x16_bf16(kf0, qf10, z16, 0, 0, 0);
        cf = __builtin_amdgcn_mfma_f32_32x32x16_bf16(kf1, qf11, cf, 0, 0, 0);
        __builtin_amdgcn_s_setprio(0);

        a0 = pgrp<0>(cf, u0, mk0, lp1);
        a1 = pgrp<1>(cf, u1, mk1, lp1);
        a2 = pgrp<2>(cf, u2, mk2, lp1);
        a3 = pgrp<3>(cf, u3, mk3, lp1);
        bf16x8 pb0, pb1;
        frags(a0, a1, a2, a3, pb0, pb1);

        __builtin_amdgcn_s_setprio(1);
        oacc1 = __builtin_amdgcn_mfma_f32_32x32x16_bf16(pb0, vf0, oacc1, 0, 0, 0);
        oacc1 = __builtin_amdgcn_mfma_f32_32x32x16_bf16(pb1, vf1, oacc1, 0, 0, 0);
        __builtin_amdgcn_s_setprio(0);
    }

    // ---- softmax denominators: hi-half reduce, then normalize + store ----
    lp0 += __shfl_xor(lp0, 32);
    lp1 += __shfl_xor(lp1, 32);
    const float li0 = 1.0f / lp0;      // valid for s = sbase + l31
    const float li1 = 1.0f / lp1;      // valid for s = sbase + 32 + l31

    float* ob = out + (size_t)inst * SEQ * DH;
    #pragma unroll
    for (int r = 0; r < 16; ++r) {
        const int srow = (r & 3) + 8 * (r >> 2) + 4 * hi;
        float i0 = __shfl(li0, srow);  // 1/l for row srow lives in lane srow
        float i1 = __shfl(li1, srow);
        ob[(size_t)(sbase + srow) * DH + l31]      = oacc0[r] * i0;
        ob[(size_t)(sbase + 32 + srow) * DH + l31] = oacc1[r] * i1;
    }
}

extern "C" void kernel_launch(void* const* d_in, const int* in_sizes, int n_in,
                              void* d_out, int out_size, void* d_ws, size_t ws_size,
                              hipStream_t stream) {
    const float* q    = (const float*)d_in[0];
    const float* k    = (const float*)d_in[1];
    const float* v    = (const float*)d_in[2];
    const float* mask = (const float*)d_in[3];
    const float* tri  = (const float*)d_in[4];
    float* out = (float*)d_out;

    attn_mfma_kernel<<<dim3(256 * 4), dim3(256), 0, stream>>>(q, k, v, mask, tri, out);
}